// Round 4
// baseline (869.438 us; speedup 1.0000x reference)
//
#include <hip/hip_runtime.h>
#include <hip/hip_bf16.h>
#include <math.h>

#define N_TOK 16384
#define DIM   256
#define HID   512
#define NEXP  16
#define NSLOT (N_TOK * 2)
#define RT    32
#define TKK   16
#define MAXT  (NSLOT / RT + NEXP)   // 1040 upper bound on total m-tiles

__device__ __forceinline__ float b2f(unsigned short u) {
  union { unsigned int i; float f; } c; c.i = ((unsigned int)u) << 16; return c.f;
}
__device__ __forceinline__ unsigned short f2b(float f) {
  union { float f; unsigned int i; } c; c.f = f;
  unsigned int r = c.i + 0x7FFFu + ((c.i >> 16) & 1u);  // round-nearest-even
  return (unsigned short)(r >> 16);
}

// ---------------- router: logits, softmax, top-2, sumprob ----------------
__global__ __launch_bounds__(256) void router_kernel(
    const float* __restrict__ x, const float* __restrict__ Wr,
    float* __restrict__ probs_out, float* __restrict__ topi_out,
    float* __restrict__ topw, int* __restrict__ sel, float* __restrict__ g_sumprob)
{
  __shared__ float lgS[16][17];
  __shared__ float exS[16][17];
  __shared__ float s_sumprob[16];
  int tid = threadIdx.x;
  int tl  = tid >> 4;          // token within block (0..15)
  int e   = tid & 15;          // expert (0..15)
  int tok = (blockIdx.x << 4) + tl;
  if (tid < 16) s_sumprob[tid] = 0.f;

  const float4* xr = (const float4*)(x + (size_t)tok * DIM);
  const float4* wr = (const float4*)(Wr + (size_t)e * DIM);
  float a0 = 0.f, a1 = 0.f, a2 = 0.f, a3 = 0.f;
  #pragma unroll 8
  for (int i = 0; i < DIM / 4; ++i) {
    float4 xa = xr[i], wa = wr[i];
    a0 += xa.x * wa.x; a1 += xa.y * wa.y; a2 += xa.z * wa.z; a3 += xa.w * wa.w;
  }
  lgS[tl][e] = (a0 + a1) + (a2 + a3);
  __syncthreads();

  float mx = -1e30f;
  #pragma unroll
  for (int j = 0; j < 16; ++j) mx = fmaxf(mx, lgS[tl][j]);
  float ex = expf(lgS[tl][e] - mx);
  exS[tl][e] = ex;
  __syncthreads();

  float s = 0.f;
  #pragma unroll
  for (int j = 0; j < 16; ++j) s += exS[tl][j];
  float p = ex / s;
  probs_out[(size_t)tok * NEXP + e] = p;
  atomicAdd(&s_sumprob[e], p);

  if (e == 0) {
    // top-2 on p = exp/sum (division, mirroring jax.nn.softmax); strict >, low index wins
    float m1 = -1.f; int i1 = 0;
    #pragma unroll
    for (int j = 0; j < 16; ++j) { float v = exS[tl][j] / s; if (v > m1) { m1 = v; i1 = j; } }
    float m2 = -1.f; int i2 = 0;
    #pragma unroll
    for (int j = 0; j < 16; ++j) { if (j == i1) continue; float v = exS[tl][j] / s; if (v > m2) { m2 = v; i2 = j; } }
    float rs = 1.0f / (m1 + m2 + 1e-9f);
    int s0 = tok * 2;
    topw[s0]     = m1 * rs;  topw[s0 + 1] = m2 * rs;
    sel[s0]      = i1;       sel[s0 + 1]  = i2;
    topi_out[s0]     = (float)i1;
    topi_out[s0 + 1] = (float)i2;
  }
  __syncthreads();
  if (tid < 16) atomicAdd(&g_sumprob[tid], s_sumprob[tid]);
}

// ---------------- placement: single block, wave e owns expert e ----------------
__global__ __launch_bounds__(1024) void placement_kernel(
    const int* __restrict__ sel, const float* __restrict__ topw,
    const float* __restrict__ g_sumprob,
    int* __restrict__ offs, int* __restrict__ toff,
    int* __restrict__ pos_of_slot, int* __restrict__ tok_of_pos,
    float* __restrict__ w_of_pos, float* __restrict__ lb_out)
{
  __shared__ int scnt[16];
  __shared__ int soffs[17];
  int tid  = threadIdx.x;
  int wv   = tid >> 6;          // expert owned by this wave (0..15)
  int lane = tid & 63;

  // pass A: count slots per expert (batched loads)
  int c = 0;
  for (int b = 0; b < NSLOT; b += 256) {
    int v0 = sel[b + lane];
    int v1 = sel[b + 64 + lane];
    int v2 = sel[b + 128 + lane];
    int v3 = sel[b + 192 + lane];
    c += __popcll(__ballot(v0 == wv));
    c += __popcll(__ballot(v1 == wv));
    c += __popcll(__ballot(v2 == wv));
    c += __popcll(__ballot(v3 == wv));
  }
  if (lane == 0) scnt[wv] = c;
  __syncthreads();

  if (tid == 0) {
    int o = 0, t = 0; float acc = 0.f;
    for (int e2 = 0; e2 < NEXP; ++e2) {
      soffs[e2] = o; offs[e2] = o; toff[e2] = t;
      o += scnt[e2];
      t += (scnt[e2] + RT - 1) / RT;
      acc += ((float)scnt[e2] / (32768.0f + 1e-9f)) * (g_sumprob[e2] * (1.0f / 16384.0f));
    }
    soffs[NEXP] = o; offs[NEXP] = o; toff[NEXP] = t;
    lb_out[0] = 0.01f * 16.0f * acc;
  }
  __syncthreads();

  // pass B: stable placement in slot order
  int cur = soffs[wv];
  unsigned long long ltm = (1ull << lane) - 1ull;
  for (int b = 0; b < NSLOT; b += 256) {
    int v0 = sel[b + lane];
    int v1 = sel[b + 64 + lane];
    int v2 = sel[b + 128 + lane];
    int v3 = sel[b + 192 + lane];
    #pragma unroll
    for (int q = 0; q < 4; ++q) {
      int s = b + q * 64 + lane;
      int v = (q == 0) ? v0 : (q == 1) ? v1 : (q == 2) ? v2 : v3;
      bool match = (v == wv);
      unsigned long long m = __ballot(match);
      if (match) {
        int p = cur + __popcll(m & ltm);
        pos_of_slot[s] = p;
        tok_of_pos[p]  = s >> 1;
        w_of_pos[p]    = topw[s];
      }
      cur += __popcll(m);
    }
  }
}

// ---------------- fused FFN: H in LDS, y = gelu(X W1) W2 * w ----------------
__global__ __launch_bounds__(256) void ffn_kernel(
    const float* __restrict__ x, const float* __restrict__ W1, const float* __restrict__ W2,
    const int* __restrict__ offs, const int* __restrict__ toff,
    const int* __restrict__ tok_of_pos, const float* __restrict__ w_of_pos,
    __hip_bfloat16* __restrict__ ybuf)
{
  __shared__ unsigned short Xs[DIM][RT + 4];   // 18,432 B
  __shared__ unsigned short Hs[HID][RT + 4];   // 36,864 B
  __shared__ float Bs[TKK][64 + 4];            //  4,352 B
  __shared__ float rw[RT];

  int w = blockIdx.x;
  if (w >= toff[NEXP]) return;
  int e = 0;
  #pragma unroll
  for (int j = 1; j < NEXP; ++j) if (w >= toff[j]) e = j;
  int base = offs[e];
  int cnt  = offs[e + 1] - base;
  int m0   = (w - toff[e]) * RT;

  int tid  = threadIdx.x;
  int trow = tid & 31;
  int seg  = tid >> 5;
  int rloc = m0 + trow;
  int tok  = (rloc < cnt) ? (tok_of_pos[base + rloc] & (N_TOK - 1)) : -1;
  if (tid < RT) rw[tid] = (m0 + tid < cnt) ? w_of_pos[base + m0 + tid] : 0.f;

  #pragma unroll
  for (int it = 0; it < 8; ++it) {
    int d = seg * 4 + it * 32;   // covers [0,256) in multiples of 4
    float4 xv = make_float4(0.f, 0.f, 0.f, 0.f);
    if (tok >= 0) xv = *(const float4*)(x + (size_t)tok * DIM + d);
    Xs[d][trow]     = f2b(xv.x);
    Xs[d + 1][trow] = f2b(xv.y);
    Xs[d + 2][trow] = f2b(xv.z);
    Xs[d + 3][trow] = f2b(xv.w);
  }

  int tr = (tid >> 4) << 1;     // 0..30 (row pair)
  int tc = (tid & 15) << 2;     // 0..60 (col quad)
  int kk = tid >> 4;            // B-staging row
  int c4 = (tid & 15) << 2;     // B-staging col quad

  // phase 1: Hs = gelu(X @ W1[e])
  const float* W1e = W1 + (size_t)e * DIM * HID;
  for (int n0 = 0; n0 < HID; n0 += 64) {
    float acc[2][4] = {{0.f,0.f,0.f,0.f},{0.f,0.f,0.f,0.f}};
    for (int kt = 0; kt < DIM / TKK; ++kt) {
      __syncthreads();
      *(float4*)&Bs[kk][c4] = *(const float4*)(W1e + (size_t)(kt * TKK + kk) * HID + n0 + c4);
      __syncthreads();
      #pragma unroll
      for (int k2 = 0; k2 < TKK; ++k2) {
        int kidx = kt * TKK + k2;
        unsigned int xx = *(const unsigned int*)&Xs[kidx][tr];
        float a0 = b2f((unsigned short)(xx & 0xFFFFu));
        float a1 = b2f((unsigned short)(xx >> 16));
        float4 b = *(const float4*)&Bs[k2][tc];
        acc[0][0] += a0 * b.x; acc[0][1] += a0 * b.y; acc[0][2] += a0 * b.z; acc[0][3] += a0 * b.w;
        acc[1][0] += a1 * b.x; acc[1][1] += a1 * b.y; acc[1][2] += a1 * b.z; acc[1][3] += a1 * b.w;
      }
    }
    #pragma unroll
    for (int i = 0; i < 2; ++i) {
      #pragma unroll
      for (int j = 0; j < 4; ++j) {
        float v = acc[i][j];
        float g = 0.5f * v * (1.0f + erff(v * 0.70710678118654752f));
        Hs[n0 + tc + j][tr + i] = f2b(g);
      }
    }
  }

  // phase 2: y = (Hs @ W2[e]) * rw
  const float* W2e = W2 + (size_t)e * HID * DIM;
  for (int n2 = 0; n2 < DIM; n2 += 64) {
    float acc[2][4] = {{0.f,0.f,0.f,0.f},{0.f,0.f,0.f,0.f}};
    for (int kt = 0; kt < HID / TKK; ++kt) {
      __syncthreads();
      *(float4*)&Bs[kk][c4] = *(const float4*)(W2e + (size_t)(kt * TKK + kk) * DIM + n2 + c4);
      __syncthreads();
      #pragma unroll
      for (int k2 = 0; k2 < TKK; ++k2) {
        int kidx = kt * TKK + k2;
        unsigned int hh = *(const unsigned int*)&Hs[kidx][tr];
        float a0 = b2f((unsigned short)(hh & 0xFFFFu));
        float a1 = b2f((unsigned short)(hh >> 16));
        float4 b = *(const float4*)&Bs[k2][tc];
        acc[0][0] += a0 * b.x; acc[0][1] += a0 * b.y; acc[0][2] += a0 * b.z; acc[0][3] += a0 * b.w;
        acc[1][0] += a1 * b.x; acc[1][1] += a1 * b.y; acc[1][2] += a1 * b.z; acc[1][3] += a1 * b.w;
      }
    }
    #pragma unroll
    for (int i = 0; i < 2; ++i) {
      int row = m0 + tr + i;
      if (row < cnt) {
        float wr_ = rw[tr + i];
        __hip_bfloat16* yp = ybuf + (size_t)(base + row) * DIM + n2 + tc;
        #pragma unroll
        for (int j = 0; j < 4; ++j) yp[j] = __float2bfloat16(acc[i][j] * wr_);
      }
    }
  }
}

// ---------------- combine + residual + LayerNorm ----------------
__global__ __launch_bounds__(256) void combine_ln_kernel(
    const float* __restrict__ x, const __hip_bfloat16* __restrict__ ybuf,
    const int* __restrict__ pos_of_slot, const float* __restrict__ gamma,
    const float* __restrict__ beta, float* __restrict__ outp)
{
  int wv = threadIdx.x >> 6, lane = threadIdx.x & 63;
  int tok = blockIdx.x * 4 + wv;
  int p0 = pos_of_slot[tok * 2];
  int p1 = pos_of_slot[tok * 2 + 1];
  p0 = min(max(p0, 0), NSLOT - 1);
  p1 = min(max(p1, 0), NSLOT - 1);
  int d0 = lane << 2;
  float4 xv = *(const float4*)(x + (size_t)tok * DIM + d0);
  const unsigned short* yb = (const unsigned short*)ybuf;
  ushort4 u0 = *(const ushort4*)(yb + (size_t)p0 * DIM + d0);
  ushort4 u1 = *(const ushort4*)(yb + (size_t)p1 * DIM + d0);
  float z0 = xv.x + b2f(u0.x) + b2f(u1.x);
  float z1 = xv.y + b2f(u0.y) + b2f(u1.y);
  float z2 = xv.z + b2f(u0.z) + b2f(u1.z);
  float z3 = xv.w + b2f(u0.w) + b2f(u1.w);
  float s = z0 + z1 + z2 + z3;
  float q = z0 * z0 + z1 * z1 + z2 * z2 + z3 * z3;
  #pragma unroll
  for (int off = 32; off > 0; off >>= 1) {
    s += __shfl_xor(s, off, 64);
    q += __shfl_xor(q, off, 64);
  }
  float mu  = s * (1.0f / 256.0f);
  float var = q * (1.0f / 256.0f) - mu * mu;
  float inv = rsqrtf(var + 1e-5f);
  float4 gv = *(const float4*)(gamma + d0);
  float4 bv = *(const float4*)(beta + d0);
  float4 ov;
  ov.x = (z0 - mu) * inv * gv.x + bv.x;
  ov.y = (z1 - mu) * inv * gv.y + bv.y;
  ov.z = (z2 - mu) * inv * gv.z + bv.z;
  ov.w = (z3 - mu) * inv * gv.w + bv.w;
  *(float4*)(outp + (size_t)tok * DIM + d0) = ov;
}

extern "C" void kernel_launch(void* const* d_in, const int* in_sizes, int n_in,
                              void* d_out, int out_size, void* d_ws, size_t ws_size,
                              hipStream_t stream)
{
  const float* x     = (const float*)d_in[0];
  const float* Wr    = (const float*)d_in[1];
  const float* W1    = (const float*)d_in[2];
  const float* W2    = (const float*)d_in[3];
  const float* gamma = (const float*)d_in[4];
  const float* beta  = (const float*)d_in[5];

  float* ob = (float*)d_out;
  float* out_main  = ob;                                             // [N*D]
  float* lb_out    = ob + (size_t)N_TOK * DIM;                       // [1]
  float* probs_out = ob + (size_t)N_TOK * DIM + 1;                   // [N*E]
  float* topi_out  = ob + (size_t)N_TOK * DIM + 1 + (size_t)N_TOK * NEXP;  // [N*K]

  char* ws = (char*)d_ws;
  float* g_sumprob   = (float*)(ws + 0);      // 16 f32 (zeroed)
  int*   offs        = (int*)(ws + 128);      // 17 ints
  int*   toff        = (int*)(ws + 256);      // 17 ints
  float* topw        = (float*)(ws + 512);                 // 128 KB
  int*   sel         = (int*)(ws + 512 + 131072);          // 128 KB
  int*   pos_of_slot = (int*)(ws + 512 + 2 * 131072);      // 128 KB
  int*   tok_of_pos  = (int*)(ws + 512 + 3 * 131072);      // 128 KB
  float* w_of_pos    = (float*)(ws + 512 + 4 * 131072);    // 128 KB
  __hip_bfloat16* ybuf = (__hip_bfloat16*)(ws + 512 + 5 * 131072);  // 16 MB; total ~16.6 MB

  hipMemsetAsync(d_ws, 0, 512, stream);
  router_kernel<<<N_TOK / 16, 256, 0, stream>>>(x, Wr, probs_out, topi_out, topw, sel, g_sumprob);
  placement_kernel<<<1, 1024, 0, stream>>>(sel, topw, g_sumprob, offs, toff,
                                           pos_of_slot, tok_of_pos, w_of_pos, lb_out);
  ffn_kernel<<<MAXT, 256, 0, stream>>>(x, W1, W2, offs, toff, tok_of_pos, w_of_pos, ybuf);
  combine_ln_kernel<<<N_TOK / 4, 256, 0, stream>>>(x, ybuf, pos_of_slot, gamma, beta, out_main);
}

// Round 5
// 407.315 us; speedup vs baseline: 2.1346x; 2.1346x over previous
//
#include <hip/hip_runtime.h>
#include <hip/hip_bf16.h>
#include <math.h>

#define N_TOK 16384
#define DIM   256
#define HID   512
#define NEXP  16
#define NSLOT (N_TOK * 2)
#define RT    32
#define MAXT  (NSLOT / RT + NEXP)   // 1040 = 8*130, upper bound on total m-tiles

typedef __attribute__((ext_vector_type(8))) short bf16x8;
typedef __attribute__((ext_vector_type(4))) float f32x4;
#define MFMA(a, b, c) __builtin_amdgcn_mfma_f32_16x16x32_bf16(a, b, c, 0, 0, 0)

__device__ __forceinline__ unsigned short f2b(float f) {
  union { float f; unsigned int i; } c; c.f = f;
  unsigned int r = c.i + 0x7FFFu + ((c.i >> 16) & 1u);  // RNE
  return (unsigned short)(r >> 16);
}

// tanh-form GELU via hw exp2/rcp: v*(1 - 1/(1+2^(c1*v + c3*v^3)))
__device__ __forceinline__ float gelu_f(float v) {
  float v2 = v * v;
  float u2 = v * fmaf(0.10294322f, v2, 2.3022082f);
  float s  = __builtin_amdgcn_exp2f(u2);
  float r  = __builtin_amdgcn_rcpf(1.0f + s);
  return fmaf(-v, r, v);
}

// ---------- prep: W1,W2 -> bf16 fragment-major; x -> bf16 row-major ----------
__global__ __launch_bounds__(256) void prep_kernel(
    const float* __restrict__ W1, const float* __restrict__ W2, const float* __restrict__ x,
    unsigned short* __restrict__ W1f, unsigned short* __restrict__ W2f, unsigned short* __restrict__ xb)
{
  int id = blockIdx.x * 256 + threadIdx.x;
  if (id < 524288) {                       // W1: idx = ((e*8+kb)*512+h)*32 + (d%32)
    int i4 = id * 4;
    int inner = i4 & 31;
    int h  = (i4 >> 5) & 511;
    int kb = (i4 >> 14) & 7;
    int e  = i4 >> 17;
    const float* src = W1 + ((size_t)(e * 256 + kb * 32 + inner) * 512 + h);
    ushort4 o;
    o.x = f2b(src[0]); o.y = f2b(src[512]); o.z = f2b(src[1024]); o.w = f2b(src[1536]);
    *(ushort4*)(W1f + i4) = o;
  } else if (id < 1048576) {               // W2: idx = ((e*16+kb)*256+d2)*32 + (h%32)
    int i4 = (id - 524288) * 4;
    int inner = i4 & 31;
    int d2 = (i4 >> 5) & 255;
    int kb = (i4 >> 13) & 15;
    int e  = i4 >> 17;
    const float* src = W2 + ((size_t)(e * 512 + kb * 32 + inner) * 256 + d2);
    ushort4 o;
    o.x = f2b(src[0]); o.y = f2b(src[256]); o.z = f2b(src[512]); o.w = f2b(src[768]);
    *(ushort4*)(W2f + i4) = o;
  } else {                                 // x: straight bf16 copy
    int j = id - 1048576;
    float4 xv = *(const float4*)(x + (size_t)j * 4);
    ushort4 o;
    o.x = f2b(xv.x); o.y = f2b(xv.y); o.z = f2b(xv.z); o.w = f2b(xv.w);
    *(ushort4*)(xb + (size_t)j * 4) = o;
  }
}

// ---------- router: one wave per token ----------
__global__ __launch_bounds__(256) void router_kernel(
    const float* __restrict__ x, const float* __restrict__ Wr,
    float* __restrict__ probs_out, float* __restrict__ topi_out,
    float* __restrict__ topw, int* __restrict__ sel, float* __restrict__ g_partial)
{
  __shared__ float sp[16];
  int tid = threadIdx.x;
  int wv = tid >> 6, lane = tid & 63;
  int tok = blockIdx.x * 4 + wv;
  int e = lane & 15, q = lane >> 4;
  if (tid < 16) sp[tid] = 0.f;
  __syncthreads();

  const float4* xr = (const float4*)(x + (size_t)tok * DIM + q * 64);
  const float4* wr = (const float4*)(Wr + (size_t)e * DIM + q * 64);
  float a0 = 0.f, a1 = 0.f, a2 = 0.f, a3 = 0.f;
  #pragma unroll
  for (int i = 0; i < 16; ++i) {
    float4 xa = xr[i], wa = wr[i];
    a0 += xa.x * wa.x; a1 += xa.y * wa.y; a2 += xa.z * wa.z; a3 += xa.w * wa.w;
  }
  float lg = (a0 + a1) + (a2 + a3);
  lg += __shfl_xor(lg, 16, 64);
  lg += __shfl_xor(lg, 32, 64);           // every lane: full logit for its e

  float mx = lg;
  #pragma unroll
  for (int o = 1; o < 16; o <<= 1) mx = fmaxf(mx, __shfl_xor(mx, o, 64));
  float ex = expf(lg - mx);
  float ssum = ex;
  #pragma unroll
  for (int o = 1; o < 16; o <<= 1) ssum += __shfl_xor(ssum, o, 64);
  float p = ex / ssum;

  if (lane < 16) {
    probs_out[(size_t)tok * NEXP + e] = p;
    atomicAdd(&sp[e], p);
  }

  // top-2 argmax (strict >, low index wins)
  float p1 = p; int i1 = e;
  #pragma unroll
  for (int o = 1; o < 16; o <<= 1) {
    float po = __shfl_xor(p1, o, 64); int io = __shfl_xor(i1, o, 64);
    if (po > p1 || (po == p1 && io < i1)) { p1 = po; i1 = io; }
  }
  float pm = (e == i1) ? -1.f : p;
  float p2 = pm; int i2 = e;
  #pragma unroll
  for (int o = 1; o < 16; o <<= 1) {
    float po = __shfl_xor(p2, o, 64); int io = __shfl_xor(i2, o, 64);
    if (po > p2 || (po == p2 && io < i2)) { p2 = po; i2 = io; }
  }
  if (lane == 0) {
    float rs = 1.0f / (p1 + p2 + 1e-9f);
    int s0 = tok * 2;
    topw[s0] = p1 * rs;  topw[s0 + 1] = p2 * rs;
    sel[s0] = i1;        sel[s0 + 1] = i2;
    topi_out[s0] = (float)i1;  topi_out[s0 + 1] = (float)i2;
  }
  __syncthreads();
  if (tid < 16) g_partial[(size_t)tid * 4096 + blockIdx.x] = sp[tid];
}

// ---------- placement: counts, offsets, lb, XCD-grouped tile table, buckets ----------
__global__ __launch_bounds__(1024) void placement_kernel(
    const int* __restrict__ sel, const float* __restrict__ topw,
    const float* __restrict__ g_partial,
    int* __restrict__ offs, int* __restrict__ perm,
    int* __restrict__ tok_of_pos, float* __restrict__ w_of_pos,
    float* __restrict__ lb_out)
{
  __shared__ int scnt[16];
  __shared__ int soffs[17];
  __shared__ float sp[16];
  int tid = threadIdx.x;
  int wv = tid >> 6, lane = tid & 63;

  // count slots per expert
  int c = 0;
  for (int b = 0; b < NSLOT; b += 256) {
    c += __popcll(__ballot(sel[b + lane] == wv));
    c += __popcll(__ballot(sel[b + 64 + lane] == wv));
    c += __popcll(__ballot(sel[b + 128 + lane] == wv));
    c += __popcll(__ballot(sel[b + 192 + lane] == wv));
  }
  if (lane == 0) scnt[wv] = c;

  // reduce per-expert sumprob (wave wv owns expert wv)
  float sacc = 0.f;
  for (int j = 0; j < 64; ++j) sacc += g_partial[(size_t)wv * 4096 + j * 64 + lane];
  #pragma unroll
  for (int o = 32; o; o >>= 1) sacc += __shfl_xor(sacc, o, 64);
  if (lane == 0) sp[wv] = sacc;
  __syncthreads();

  if (tid == 0) {
    int o = 0; float acc = 0.f;
    for (int e2 = 0; e2 < NEXP; ++e2) {
      soffs[e2] = o; offs[e2] = o;
      o += scnt[e2];
      acc += ((float)scnt[e2] / (32768.0f + 1e-9f)) * (sp[e2] * (1.0f / 16384.0f));
    }
    soffs[NEXP] = o; offs[NEXP] = o;
    lb_out[0] = 0.01f * 16.0f * acc;
    // tile table grouped by expert%8 (XCD pinning)
    int pos = 0;
    for (int g = 0; g < 8; ++g)
      for (int h = 0; h < 2; ++h) {
        int e2 = g + h * 8;
        int nt = (scnt[e2] + RT - 1) / RT;
        for (int mt = 0; mt < nt; ++mt) perm[pos++] = (e2 << 16) | mt;
      }
    for (; pos < MAXT; ++pos) perm[pos] = -1;
  }
  __syncthreads();

  // stable placement in slot order
  int cur = soffs[wv];
  unsigned long long ltm = (1ull << lane) - 1ull;
  for (int b = 0; b < NSLOT; b += 256) {
    #pragma unroll
    for (int qq = 0; qq < 4; ++qq) {
      int s = b + qq * 64 + lane;
      bool match = (sel[s] == wv);
      unsigned long long m = __ballot(match);
      if (match) {
        int pp = cur + __popcll(m & ltm);
        tok_of_pos[pp] = s >> 1;
        w_of_pos[pp]   = topw[s];
      }
      cur += __popcll(m);
    }
  }
}

// ---------- fused FFN: MFMA GEMM1(gelu) + GEMM2, atomic scatter into zbuf ----------
__global__ __launch_bounds__(256, 3) void ffn_kernel(
    const unsigned short* __restrict__ xb,
    const unsigned short* __restrict__ W1f, const unsigned short* __restrict__ W2f,
    const int* __restrict__ offs, const int* __restrict__ perm,
    const int* __restrict__ tok_of_pos, const float* __restrict__ w_of_pos,
    float* __restrict__ zbuf)
{
  __shared__ __align__(16) unsigned short As[8 * 32 * 32];    // 16 KB: kb*1024 + row*32 + k%32
  __shared__ __align__(16) unsigned short Hs[16 * 32 * 32];   // 32 KB: kb2*1024 + row*32 + k%32
  __shared__ float rwS[RT];
  __shared__ int   tokS[RT];

  int b = blockIdx.x;
  int rr = (b & 7) * (MAXT / 8) + (b >> 3);   // XCD-pinned tile pick
  int pv = perm[rr];
  if (pv < 0) return;
  int e = pv >> 16, mtile = pv & 0xFFFF;
  int base = offs[e];
  int cnt  = offs[e + 1] - base;
  int m0   = mtile * RT;

  int tid = threadIdx.x;
  if (tid < RT) {
    int rl = m0 + tid;
    tokS[tid] = (rl < cnt) ? tok_of_pos[base + rl] : -1;
    rwS[tid]  = (rl < cnt) ? w_of_pos[base + rl] : 0.f;
  }
  __syncthreads();

  // gather X rows (bf16) into As fragment layout
  {
    int cb = tid & 31;                 // 16B chunk (8 bf16) within row
    int r0 = tid >> 5;
    int lo = (cb >> 2) * 1024 + (cb & 3) * 8;
    #pragma unroll
    for (int q = 0; q < 4; ++q) {
      int row = r0 + q * 8;
      int tk = tokS[row];
      bf16x8 v = {0, 0, 0, 0, 0, 0, 0, 0};
      if (tk >= 0) v = *(const bf16x8*)(xb + (size_t)tk * DIM + cb * 8);
      *(bf16x8*)&As[lo + row * 32] = v;
    }
  }
  __syncthreads();

  int lane = tid & 63;
  int w = tid >> 6;
  int l15 = lane & 15, g = lane >> 4;

  // ---- GEMM1: H = gelu(A @ W1e), wave w owns cols [w*128, w*128+128) ----
  bf16x8 af[2][8];
  #pragma unroll
  for (int mf = 0; mf < 2; ++mf)
    #pragma unroll
    for (int kb = 0; kb < 8; ++kb)
      af[mf][kb] = *(bf16x8*)&As[kb * 1024 + (mf * 16 + l15) * 32 + g * 8];

  const unsigned short* W1e = W1f + (size_t)e * (8 * 512 * 32);
  #pragma unroll
  for (int cf = 0; cf < 8; ++cf) {
    int col0 = w * 128 + cf * 16;
    f32x4 ac0 = {0.f, 0.f, 0.f, 0.f}, ac1 = {0.f, 0.f, 0.f, 0.f};
    #pragma unroll
    for (int kb = 0; kb < 8; ++kb) {
      bf16x8 bfr = *(const bf16x8*)(W1e + (size_t)(kb * 512 + col0 + l15) * 32 + g * 8);
      ac0 = MFMA(af[0][kb], bfr, ac0);
      ac1 = MFMA(af[1][kb], bfr, ac1);
    }
    int col = col0 + l15;
    int kbo = (col >> 5) * 1024 + (col & 31);
    #pragma unroll
    for (int reg = 0; reg < 4; ++reg) {
      int row0 = g * 4 + reg;
      Hs[kbo + row0 * 32]        = f2b(gelu_f(ac0[reg]));
      Hs[kbo + (row0 + 16) * 32] = f2b(gelu_f(ac1[reg]));
    }
  }
  __syncthreads();

  // ---- GEMM2: y = (H @ W2e) * w, wave w owns cols [w*64, w*64+64) ----
  bf16x8 hf[2][16];
  #pragma unroll
  for (int mf = 0; mf < 2; ++mf)
    #pragma unroll
    for (int kb = 0; kb < 16; ++kb)
      hf[mf][kb] = *(bf16x8*)&Hs[kb * 1024 + (mf * 16 + l15) * 32 + g * 8];

  const unsigned short* W2e = W2f + (size_t)e * (16 * 256 * 32);
  #pragma unroll
  for (int cf = 0; cf < 4; ++cf) {
    int col0 = w * 64 + cf * 16;
    f32x4 ac0 = {0.f, 0.f, 0.f, 0.f}, ac1 = {0.f, 0.f, 0.f, 0.f};
    #pragma unroll
    for (int kb = 0; kb < 16; ++kb) {
      bf16x8 bfr = *(const bf16x8*)(W2e + (size_t)(kb * 256 + col0 + l15) * 32 + g * 8);
      ac0 = MFMA(hf[0][kb], bfr, ac0);
      ac1 = MFMA(hf[1][kb], bfr, ac1);
    }
    int col = col0 + l15;
    #pragma unroll
    for (int reg = 0; reg < 4; ++reg) {
      int row0 = g * 4 + reg;
      int t0 = tokS[row0], t1 = tokS[row0 + 16];
      if (t0 >= 0) atomicAdd(zbuf + (size_t)t0 * DIM + col, ac0[reg] * rwS[row0]);
      if (t1 >= 0) atomicAdd(zbuf + (size_t)t1 * DIM + col, ac1[reg] * rwS[row0 + 16]);
    }
  }
}

// ---------- combine + residual + LayerNorm ----------
__global__ __launch_bounds__(256) void combine_ln_kernel(
    const float* __restrict__ x, const float* __restrict__ zbuf,
    const float* __restrict__ gamma, const float* __restrict__ beta,
    float* __restrict__ outp)
{
  int wv = threadIdx.x >> 6, lane = threadIdx.x & 63;
  int tok = blockIdx.x * 4 + wv;
  int d0 = lane << 2;
  float4 xv = *(const float4*)(x + (size_t)tok * DIM + d0);
  float4 mv = *(const float4*)(zbuf + (size_t)tok * DIM + d0);
  float z0 = xv.x + mv.x, z1 = xv.y + mv.y, z2 = xv.z + mv.z, z3 = xv.w + mv.w;
  float s = z0 + z1 + z2 + z3;
  float q = z0 * z0 + z1 * z1 + z2 * z2 + z3 * z3;
  #pragma unroll
  for (int off = 32; off > 0; off >>= 1) {
    s += __shfl_xor(s, off, 64);
    q += __shfl_xor(q, off, 64);
  }
  float mu  = s * (1.0f / 256.0f);
  float var = q * (1.0f / 256.0f) - mu * mu;
  float inv = rsqrtf(var + 1e-5f);
  float4 gv = *(const float4*)(gamma + d0);
  float4 bv = *(const float4*)(beta + d0);
  float4 ov;
  ov.x = (z0 - mu) * inv * gv.x + bv.x;
  ov.y = (z1 - mu) * inv * gv.y + bv.y;
  ov.z = (z2 - mu) * inv * gv.z + bv.z;
  ov.w = (z3 - mu) * inv * gv.w + bv.w;
  *(float4*)(outp + (size_t)tok * DIM + d0) = ov;
}

extern "C" void kernel_launch(void* const* d_in, const int* in_sizes, int n_in,
                              void* d_out, int out_size, void* d_ws, size_t ws_size,
                              hipStream_t stream)
{
  const float* x     = (const float*)d_in[0];
  const float* Wr    = (const float*)d_in[1];
  const float* W1    = (const float*)d_in[2];
  const float* W2    = (const float*)d_in[3];
  const float* gamma = (const float*)d_in[4];
  const float* beta  = (const float*)d_in[5];

  float* ob = (float*)d_out;
  float* out_main  = ob;
  float* lb_out    = ob + (size_t)N_TOK * DIM;
  float* probs_out = ob + (size_t)N_TOK * DIM + 1;
  float* topi_out  = ob + (size_t)N_TOK * DIM + 1 + (size_t)N_TOK * NEXP;

  char* ws = (char*)d_ws;
  float* g_partial  = (float*)(ws + 0);                 // 16*4096 f32 = 256 KB
  float* topw       = (float*)(ws + 262144);            // 128 KB
  int*   sel        = (int*)(ws + 393216);              // 128 KB
  int*   tok_of_pos = (int*)(ws + 524288);              // 128 KB
  float* w_of_pos   = (float*)(ws + 655360);            // 128 KB
  int*   offs       = (int*)(ws + 786432);              // 17 ints
  int*   perm       = (int*)(ws + 786688);              // 1040 ints
  unsigned short* xb  = (unsigned short*)(ws + 1048576);   // 8 MB
  unsigned short* W1f = (unsigned short*)(ws + 9437184);   // 4 MB
  unsigned short* W2f = (unsigned short*)(ws + 13631488);  // 4 MB
  float* zbuf       = (float*)(ws + 17825792);             // 16 MB; total ~33 MB

  hipMemsetAsync(zbuf, 0, (size_t)N_TOK * DIM * 4, stream);
  prep_kernel<<<8192, 256, 0, stream>>>(W1, W2, x, W1f, W2f, xb);
  router_kernel<<<N_TOK / 4, 256, 0, stream>>>(x, Wr, probs_out, topi_out, topw, sel, g_partial);
  placement_kernel<<<1, 1024, 0, stream>>>(sel, topw, g_partial, offs, perm,
                                           tok_of_pos, w_of_pos, lb_out);
  ffn_kernel<<<MAXT, 256, 0, stream>>>(xb, W1f, W2f, offs, perm, tok_of_pos, w_of_pos, zbuf);
  combine_ln_kernel<<<N_TOK / 4, 256, 0, stream>>>(x, zbuf, gamma, beta, out_main);
}

// Round 6
// 240.079 us; speedup vs baseline: 3.6215x; 1.6966x over previous
//
#include <hip/hip_runtime.h>
#include <hip/hip_bf16.h>
#include <math.h>

#define N_TOK 16384
#define DIM   256
#define HID   512
#define NEXP  16
#define NSLOT (N_TOK * 2)
#define RT    32
#define MAXT  (NSLOT / RT + NEXP)   // 1040 = 8*130 upper bound on total m-tiles

typedef __attribute__((ext_vector_type(8))) short bf16x8;
typedef __attribute__((ext_vector_type(4))) float f32x4;
#define MFMA(a, b, c) __builtin_amdgcn_mfma_f32_16x16x32_bf16(a, b, c, 0, 0, 0)

__device__ __forceinline__ unsigned short f2b(float f) {
  union { float f; unsigned int i; } c; c.f = f;
  unsigned int r = c.i + 0x7FFFu + ((c.i >> 16) & 1u);  // RNE
  return (unsigned short)(r >> 16);
}

// tanh-form GELU via hw exp2/rcp
__device__ __forceinline__ float gelu_f(float v) {
  float v2 = v * v;
  float u2 = v * fmaf(0.10294322f, v2, 2.3022082f);
  float s  = __builtin_amdgcn_exp2f(u2);
  float r  = __builtin_amdgcn_rcpf(1.0f + s);
  return fmaf(-v, r, v);
}

// ---------- prep: W1,W2 -> bf16 fragment-major; x -> bf16 row-major ----------
__global__ __launch_bounds__(256) void prep_kernel(
    const float* __restrict__ W1, const float* __restrict__ W2, const float* __restrict__ x,
    unsigned short* __restrict__ W1f, unsigned short* __restrict__ W2f, unsigned short* __restrict__ xb)
{
  int id = blockIdx.x * 256 + threadIdx.x;
  if (id < 524288) {                       // W1f: ((e*8+kb)*512+h)*32 + (d%32)
    int i4 = id * 4;
    int inner = i4 & 31;
    int h  = (i4 >> 5) & 511;
    int kb = (i4 >> 14) & 7;
    int e  = i4 >> 17;
    const float* src = W1 + ((size_t)(e * 256 + kb * 32 + inner) * 512 + h);
    ushort4 o;
    o.x = f2b(src[0]); o.y = f2b(src[512]); o.z = f2b(src[1024]); o.w = f2b(src[1536]);
    *(ushort4*)(W1f + i4) = o;
  } else if (id < 1048576) {               // W2f: ((e*16+kb)*256+d2)*32 + (h%32)
    int i4 = (id - 524288) * 4;
    int inner = i4 & 31;
    int d2 = (i4 >> 5) & 255;
    int kb = (i4 >> 13) & 15;
    int e  = i4 >> 17;
    const float* src = W2 + ((size_t)(e * 512 + kb * 32 + inner) * 256 + d2);
    ushort4 o;
    o.x = f2b(src[0]); o.y = f2b(src[256]); o.z = f2b(src[512]); o.w = f2b(src[768]);
    *(ushort4*)(W2f + i4) = o;
  } else {                                 // x: straight bf16 copy
    int j = id - 1048576;
    float4 xv = *(const float4*)(x + (size_t)j * 4);
    ushort4 o;
    o.x = f2b(xv.x); o.y = f2b(xv.y); o.z = f2b(xv.z); o.w = f2b(xv.w);
    *(ushort4*)(xb + (size_t)j * 4) = o;
  }
}

// ---------- router: one wave per token ----------
__global__ __launch_bounds__(256) void router_kernel(
    const float* __restrict__ x, const float* __restrict__ Wr,
    float* __restrict__ probs_out, float* __restrict__ topi_out,
    float* __restrict__ topw, int* __restrict__ sel, float* __restrict__ g_partial)
{
  __shared__ float sp[16];
  int tid = threadIdx.x;
  int wv = tid >> 6, lane = tid & 63;
  int tok = blockIdx.x * 4 + wv;
  int e = lane & 15, q = lane >> 4;
  if (tid < 16) sp[tid] = 0.f;
  __syncthreads();

  const float4* xr = (const float4*)(x + (size_t)tok * DIM + q * 64);
  const float4* wr = (const float4*)(Wr + (size_t)e * DIM + q * 64);
  float a0 = 0.f, a1 = 0.f, a2 = 0.f, a3 = 0.f;
  #pragma unroll
  for (int i = 0; i < 16; ++i) {
    float4 xa = xr[i], wa = wr[i];
    a0 += xa.x * wa.x; a1 += xa.y * wa.y; a2 += xa.z * wa.z; a3 += xa.w * wa.w;
  }
  float lg = (a0 + a1) + (a2 + a3);
  lg += __shfl_xor(lg, 16, 64);
  lg += __shfl_xor(lg, 32, 64);           // every lane: full logit for its e

  float mx = lg;
  #pragma unroll
  for (int o = 1; o < 16; o <<= 1) mx = fmaxf(mx, __shfl_xor(mx, o, 64));
  float ex = expf(lg - mx);
  float ssum = ex;
  #pragma unroll
  for (int o = 1; o < 16; o <<= 1) ssum += __shfl_xor(ssum, o, 64);
  float p = ex / ssum;

  if (lane < 16) {
    probs_out[(size_t)tok * NEXP + e] = p;
    atomicAdd(&sp[e], p);
  }

  // top-2 argmax (strict >, low index wins)
  float p1 = p; int i1 = e;
  #pragma unroll
  for (int o = 1; o < 16; o <<= 1) {
    float po = __shfl_xor(p1, o, 64); int io = __shfl_xor(i1, o, 64);
    if (po > p1 || (po == p1 && io < i1)) { p1 = po; i1 = io; }
  }
  float pm = (e == i1) ? -1.f : p;
  float p2 = pm; int i2 = e;
  #pragma unroll
  for (int o = 1; o < 16; o <<= 1) {
    float po = __shfl_xor(p2, o, 64); int io = __shfl_xor(i2, o, 64);
    if (po > p2 || (po == p2 && io < i2)) { p2 = po; i2 = io; }
  }
  if (lane == 0) {
    float rs = 1.0f / (p1 + p2 + 1e-9f);
    int s0 = tok * 2;
    topw[s0] = p1 * rs;  topw[s0 + 1] = p2 * rs;
    sel[s0] = i1;        sel[s0 + 1] = i2;
    topi_out[s0] = (float)i1;  topi_out[s0 + 1] = (float)i2;
  }
  __syncthreads();
  if (tid < 16) g_partial[(size_t)tid * 4096 + blockIdx.x] = sp[tid];
}

// ---------- scatter: parallel bucket fill into per-expert arenas ----------
__global__ __launch_bounds__(256) void scatter_kernel(
    const int* __restrict__ sel, const float* __restrict__ topw,
    int* __restrict__ cursors, int* __restrict__ tok_of_pos, float* __restrict__ w_of_pos)
{
  __shared__ int bcnt[16];
  __shared__ int bbase[16];
  int tid = threadIdx.x;
  if (tid < 16) bcnt[tid] = 0;
  __syncthreads();
  int s = blockIdx.x * 256 + tid;      // NSLOT = 128*256 exact
  int e = sel[s];
  int my = atomicAdd(&bcnt[e], 1);
  __syncthreads();
  if (tid < 16) bbase[tid] = atomicAdd(&cursors[tid], bcnt[tid]);
  __syncthreads();
  int idx = e * NSLOT + bbase[e] + my;
  tok_of_pos[idx] = s >> 1;
  w_of_pos[idx]   = topw[s];
}

// ---------- stats: lb_loss + XCD-grouped tile table ----------
__global__ __launch_bounds__(1024) void stats_kernel(
    const int* __restrict__ cursors, const float* __restrict__ g_partial,
    int* __restrict__ perm, float* __restrict__ lb_out)
{
  __shared__ float sp[16];
  int tid = threadIdx.x;
  int wv = tid >> 6, lane = tid & 63;
  float sacc = 0.f;
  #pragma unroll
  for (int j = 0; j < 64; ++j) sacc += g_partial[(size_t)wv * 4096 + j * 64 + lane];
  #pragma unroll
  for (int o = 32; o; o >>= 1) sacc += __shfl_xor(sacc, o, 64);
  if (lane == 0) sp[wv] = sacc;
  __syncthreads();

  if (tid == 0) {
    float acc = 0.f;
    for (int e = 0; e < NEXP; ++e)
      acc += ((float)cursors[e] / (32768.0f + 1e-9f)) * (sp[e] * (1.0f / 16384.0f));
    lb_out[0] = 0.01f * 16.0f * acc;
    int pos = 0;
    for (int g = 0; g < 8; ++g)
      for (int h = 0; h < 2; ++h) {
        int e = g + h * 8;
        int nt = (cursors[e] + RT - 1) / RT;
        for (int mt = 0; mt < nt; ++mt) perm[pos++] = (e << 16) | mt;
      }
    for (; pos < MAXT; ++pos) perm[pos] = -1;
  }
}

// ---------- fused FFN: MFMA GEMM1(gelu) + GEMM2, atomic scatter into zbuf ----------
__global__ __launch_bounds__(256, 3) void ffn_kernel(
    const unsigned short* __restrict__ xb,
    const unsigned short* __restrict__ W1f, const unsigned short* __restrict__ W2f,
    const int* __restrict__ cursors, const int* __restrict__ perm,
    const int* __restrict__ tok_of_pos, const float* __restrict__ w_of_pos,
    float* __restrict__ zbuf)
{
  __shared__ __align__(16) unsigned short As[8 * 32 * 32];    // 16 KB
  __shared__ __align__(16) unsigned short Hs[16 * 32 * 32];   // 32 KB
  __shared__ float rwS[RT];
  __shared__ int   tokS[RT];

  int b = blockIdx.x;
  int rr = (b & 7) * (MAXT / 8) + (b >> 3);   // XCD-pinned tile pick
  int pv = perm[rr];
  if (pv < 0) return;
  int e = pv >> 16, mtile = pv & 0xFFFF;
  int cnt = cursors[e];
  int base = e * NSLOT;
  int m0 = mtile * RT;

  int tid = threadIdx.x;
  if (tid < RT) {
    int rl = m0 + tid;
    tokS[tid] = (rl < cnt) ? tok_of_pos[base + rl] : -1;
    rwS[tid]  = (rl < cnt) ? w_of_pos[base + rl] : 0.f;
  }
  __syncthreads();

  // gather X rows (bf16) into As fragment layout
  {
    int cb = tid & 31;
    int r0 = tid >> 5;
    int lo = (cb >> 2) * 1024 + (cb & 3) * 8;
    #pragma unroll
    for (int q = 0; q < 4; ++q) {
      int row = r0 + q * 8;
      int tk = tokS[row];
      bf16x8 v = {0, 0, 0, 0, 0, 0, 0, 0};
      if (tk >= 0) v = *(const bf16x8*)(xb + (size_t)tk * DIM + cb * 8);
      *(bf16x8*)&As[lo + row * 32] = v;
    }
  }
  __syncthreads();

  int lane = tid & 63;
  int w = tid >> 6;
  int l15 = lane & 15, g = lane >> 4;

  // ---- GEMM1: H = gelu(A @ W1e), wave w owns cols [w*128, w*128+128) ----
  bf16x8 af[2][8];
  #pragma unroll
  for (int mf = 0; mf < 2; ++mf)
    #pragma unroll
    for (int kb = 0; kb < 8; ++kb)
      af[mf][kb] = *(bf16x8*)&As[kb * 1024 + (mf * 16 + l15) * 32 + g * 8];

  const unsigned short* W1e = W1f + (size_t)e * (8 * 512 * 32);
  #pragma unroll
  for (int cf = 0; cf < 8; ++cf) {
    int col0 = w * 128 + cf * 16;
    f32x4 ac0 = {0.f, 0.f, 0.f, 0.f}, ac1 = {0.f, 0.f, 0.f, 0.f};
    #pragma unroll
    for (int kb = 0; kb < 8; ++kb) {
      bf16x8 bfr = *(const bf16x8*)(W1e + (size_t)(kb * 512 + col0 + l15) * 32 + g * 8);
      ac0 = MFMA(af[0][kb], bfr, ac0);
      ac1 = MFMA(af[1][kb], bfr, ac1);
    }
    int col = col0 + l15;
    int kbo = (col >> 5) * 1024 + (col & 31);
    #pragma unroll
    for (int reg = 0; reg < 4; ++reg) {
      int row0 = g * 4 + reg;
      Hs[kbo + row0 * 32]        = f2b(gelu_f(ac0[reg]));
      Hs[kbo + (row0 + 16) * 32] = f2b(gelu_f(ac1[reg]));
    }
  }
  __syncthreads();

  // ---- GEMM2: y = (H @ W2e) * w, wave w owns cols [w*64, w*64+64), mf-outer ----
  const unsigned short* W2e = W2f + (size_t)e * (16 * 256 * 32);
  #pragma unroll
  for (int mf = 0; mf < 2; ++mf) {
    bf16x8 hf[16];
    #pragma unroll
    for (int kb = 0; kb < 16; ++kb)
      hf[kb] = *(bf16x8*)&Hs[kb * 1024 + (mf * 16 + l15) * 32 + g * 8];

    f32x4 ac[4];
    #pragma unroll
    for (int cf = 0; cf < 4; ++cf) ac[cf] = (f32x4){0.f, 0.f, 0.f, 0.f};

    #pragma unroll
    for (int kb = 0; kb < 16; ++kb) {
      #pragma unroll
      for (int cf = 0; cf < 4; ++cf) {
        bf16x8 bfr = *(const bf16x8*)(W2e + (size_t)(kb * 256 + w * 64 + cf * 16 + l15) * 32 + g * 8);
        ac[cf] = MFMA(hf[kb], bfr, ac[cf]);
      }
    }

    #pragma unroll
    for (int cf = 0; cf < 4; ++cf) {
      int col = w * 64 + cf * 16 + l15;
      #pragma unroll
      for (int reg = 0; reg < 4; ++reg) {
        int row = mf * 16 + g * 4 + reg;
        int t = tokS[row];
        if (t >= 0) atomicAdd(zbuf + (size_t)t * DIM + col, ac[cf][reg] * rwS[row]);
      }
    }
  }
}

// ---------- combine + residual + LayerNorm ----------
__global__ __launch_bounds__(256) void combine_ln_kernel(
    const float* __restrict__ x, const float* __restrict__ zbuf,
    const float* __restrict__ gamma, const float* __restrict__ beta,
    float* __restrict__ outp)
{
  int wv = threadIdx.x >> 6, lane = threadIdx.x & 63;
  int tok = blockIdx.x * 4 + wv;
  int d0 = lane << 2;
  float4 xv = *(const float4*)(x + (size_t)tok * DIM + d0);
  float4 mv = *(const float4*)(zbuf + (size_t)tok * DIM + d0);
  float z0 = xv.x + mv.x, z1 = xv.y + mv.y, z2 = xv.z + mv.z, z3 = xv.w + mv.w;
  float s = z0 + z1 + z2 + z3;
  float q = z0 * z0 + z1 * z1 + z2 * z2 + z3 * z3;
  #pragma unroll
  for (int off = 32; off > 0; off >>= 1) {
    s += __shfl_xor(s, off, 64);
    q += __shfl_xor(q, off, 64);
  }
  float mu  = s * (1.0f / 256.0f);
  float var = q * (1.0f / 256.0f) - mu * mu;
  float inv = rsqrtf(var + 1e-5f);
  float4 gv = *(const float4*)(gamma + d0);
  float4 bv = *(const float4*)(beta + d0);
  float4 ov;
  ov.x = (z0 - mu) * inv * gv.x + bv.x;
  ov.y = (z1 - mu) * inv * gv.y + bv.y;
  ov.z = (z2 - mu) * inv * gv.z + bv.z;
  ov.w = (z3 - mu) * inv * gv.w + bv.w;
  *(float4*)(outp + (size_t)tok * DIM + d0) = ov;
}

extern "C" void kernel_launch(void* const* d_in, const int* in_sizes, int n_in,
                              void* d_out, int out_size, void* d_ws, size_t ws_size,
                              hipStream_t stream)
{
  const float* x     = (const float*)d_in[0];
  const float* Wr    = (const float*)d_in[1];
  const float* W1    = (const float*)d_in[2];
  const float* W2    = (const float*)d_in[3];
  const float* gamma = (const float*)d_in[4];
  const float* beta  = (const float*)d_in[5];

  float* ob = (float*)d_out;
  float* out_main  = ob;
  float* lb_out    = ob + (size_t)N_TOK * DIM;
  float* probs_out = ob + (size_t)N_TOK * DIM + 1;
  float* topi_out  = ob + (size_t)N_TOK * DIM + 1 + (size_t)N_TOK * NEXP;

  char* ws = (char*)d_ws;
  int*   cursors    = (int*)(ws + 0);                    // 64 B [zeroed]
  int*   perm       = (int*)(ws + 1024);                 // 1040 ints
  float* g_partial  = (float*)(ws + 65536);              // 256 KB
  float* topw       = (float*)(ws + 327680);             // 128 KB
  int*   sel        = (int*)(ws + 458752);               // 128 KB
  int*   tok_of_pos = (int*)(ws + 589824);               // 2 MB (16 arenas x 32768)
  float* w_of_pos   = (float*)(ws + 2686976);            // 2 MB
  unsigned short* xb  = (unsigned short*)(ws + 4980736);    // 8 MB
  unsigned short* W1f = (unsigned short*)(ws + 13369344);   // 4 MB
  unsigned short* W2f = (unsigned short*)(ws + 17563648);   // 4 MB
  float* zbuf       = (float*)(ws + 21757952);              // 16 MB; total ~36.7 MB

  hipMemsetAsync(cursors, 0, 64, stream);
  hipMemsetAsync(zbuf, 0, (size_t)N_TOK * DIM * 4, stream);
  prep_kernel<<<8192, 256, 0, stream>>>(W1, W2, x, W1f, W2f, xb);
  router_kernel<<<N_TOK / 4, 256, 0, stream>>>(x, Wr, probs_out, topi_out, topw, sel, g_partial);
  scatter_kernel<<<NSLOT / 256, 256, 0, stream>>>(sel, topw, cursors, tok_of_pos, w_of_pos);
  stats_kernel<<<1, 1024, 0, stream>>>(cursors, g_partial, perm, lb_out);
  ffn_kernel<<<MAXT, 256, 0, stream>>>(xb, W1f, W2f, cursors, perm, tok_of_pos, w_of_pos, zbuf);
  combine_ln_kernel<<<N_TOK / 4, 256, 0, stream>>>(x, zbuf, gamma, beta, out_main);
}